// Round 8
// baseline (208.865 us; speedup 1.0000x reference)
//
#include <hip/hip_runtime.h>
#include <hip/hip_bf16.h>
#include <math.h>

#define NCLS 80
#define TOPK_N 1000
#define CAND_CAP 12288
#define T0 0.91f                // fast-path score threshold (exactness gated)
#define NB2 8192                // fallback LDS histogram bins = key >> 17
#define RBINS 3072              // rank bins (k4 counting sort)
#define RBIN_LO 0x3F680000u     // float bits of ~0.90625
#define ANCH_INV 524287         // 2^19-1, anchor < 300000

// ---- workspace layout (bytes), M = 300000 ----
#define WS_SCORES   0           // 300000 f32 (fallback only)
#define WS_CAND     1200000     // 12288 u64 composite keys
#define WS_TKSCORE  1298304     // 1000 f32
#define WS_TKLABEL  1302304     // 1000 i32
#define WS_BOXES    1306304     // 1000 float4
#define WS_OBX      1322304     // 1000 float4 (class-offset boxes)
#define WS_AREAS    1338304     // 1000 f32
#define WS_MASK     1342304     // 1000 * 16 u64 transposed sup mask
#define WS_META     1470304     // [0]=unused, [2]=fast counter, [3]=fb counter
// end = 1,470,368 B

typedef unsigned long long u64;

__device__ __forceinline__ float sigmoidf_(float x) {
    return 1.0f / (1.0f + expf(-x));
}

// composite key: [50:19]=score bits, [18:0]=(2^19-1-anchor).
// u64 descending == (score desc, anchor asc); (score,anchor) unique.
__device__ __forceinline__ u64 make_key2(unsigned s32, int anchor) {
    return ((u64)s32 << 19) | (unsigned)(ANCH_INV - anchor);
}

// BIN 0 = HIGHEST scores (descending bins): ascending-bin exclusive prefix
// sum = "# elements in higher-score bins" = correct rank base.
__device__ __forceinline__ int key_bin(u64 k) {
    unsigned s32 = (unsigned)(k >> 19);
    int d = (int)(s32 - RBIN_LO);
    if (d < 0) d = 0;
    int b = d >> 9;
    if (b > RBINS - 1) b = RBINS - 1;
    return (RBINS - 1) - b;
}

// row max+argmax over 80 classes with 16 lanes (l = lane & 15), first-max tie
__device__ __forceinline__ void rowmax16(const float4* row, int l,
                                         float& bv, int& bc) {
    float4 v4 = row[l];
    bv = v4.x; bc = l * 4;
    if (v4.y > bv) { bv = v4.y; bc = l * 4 + 1; }
    if (v4.z > bv) { bv = v4.z; bc = l * 4 + 2; }
    if (v4.w > bv) { bv = v4.w; bc = l * 4 + 3; }
    if (l < 4) {
        float4 w4 = row[16 + l];
        int cb = 64 + l * 4;
        if (w4.x > bv) { bv = w4.x; bc = cb; }
        if (w4.y > bv) { bv = w4.y; bc = cb + 1; }
        if (w4.z > bv) { bv = w4.z; bc = cb + 2; }
        if (w4.w > bv) { bv = w4.w; bc = cb + 3; }
    }
    #pragma unroll
    for (int m = 8; m >= 1; m >>= 1) {
        float ov = __shfl_xor(bv, m);
        int oc = __shfl_xor(bc, m);
        if (ov > bv || (ov == bv && oc < bc)) { bv = ov; bc = oc; }
    }
}

// K1 (fast path): max-only score scan. 16-lane group handles 4 anchors.
// Candidates appended via LDS block aggregation (<=1 global atomic/block).
__global__ void __launch_bounds__(256)
k1_scores(const float* __restrict__ obj,
          const float* __restrict__ cls,
          u64* __restrict__ cand,
          int* __restrict__ counter, int M) {
    __shared__ int lcount, lbase;
    __shared__ u64 lkeys[64];
    int t = threadIdx.x;
    if (t == 0) lcount = 0;
    __syncthreads();
    int l = t & 15;
    int grp = t >> 4;                         // 16 groups/block
    int base = blockIdx.x * 64 + grp * 4;     // 4 anchors/group
    if (base < M) {                           // uniform per group; M%4==0
        const float4* p = (const float4*)(cls + (size_t)base * NCLS);
        float4 a0 = p[l], a1 = p[20 + l], a2 = p[40 + l], a3 = p[60 + l];
        float m0 = fmaxf(fmaxf(a0.x, a0.y), fmaxf(a0.z, a0.w));
        float m1 = fmaxf(fmaxf(a1.x, a1.y), fmaxf(a1.z, a1.w));
        float m2 = fmaxf(fmaxf(a2.x, a2.y), fmaxf(a2.z, a2.w));
        float m3 = fmaxf(fmaxf(a3.x, a3.y), fmaxf(a3.z, a3.w));
        if (l < 4) {                          // 16-float tails of each row
            float4 b0 = p[16 + l], b1 = p[36 + l], b2 = p[56 + l], b3 = p[76 + l];
            m0 = fmaxf(m0, fmaxf(fmaxf(b0.x, b0.y), fmaxf(b0.z, b0.w)));
            m1 = fmaxf(m1, fmaxf(fmaxf(b1.x, b1.y), fmaxf(b1.z, b1.w)));
            m2 = fmaxf(m2, fmaxf(fmaxf(b2.x, b2.y), fmaxf(b2.z, b2.w)));
            m3 = fmaxf(m3, fmaxf(fmaxf(b3.x, b3.y), fmaxf(b3.z, b3.w)));
        }
        #pragma unroll
        for (int s = 8; s >= 1; s >>= 1) {
            m0 = fmaxf(m0, __shfl_xor(m0, s));
            m1 = fmaxf(m1, __shfl_xor(m1, s));
            m2 = fmaxf(m2, __shfl_xor(m2, s));
            m3 = fmaxf(m3, __shfl_xor(m3, s));
        }
        if (l < 4) {
            float mm = (l < 2) ? ((l == 0) ? m0 : m1) : ((l == 2) ? m2 : m3);
            int anchor = base + l;
            float score = sqrtf(sigmoidf_(obj[anchor]) * sigmoidf_(mm));
            if (score > T0) {
                int pos = atomicAdd(&lcount, 1);
                lkeys[pos] = make_key2(__float_as_uint(score), anchor);
            }
        }
    }
    __syncthreads();
    if (t == 0 && lcount > 0) lbase = atomicAdd(counter, lcount);
    __syncthreads();
    int n = lcount;
    if (t < n) {
        int pos = lbase + t;
        if (pos < CAND_CAP) cand[pos] = lkeys[t];
    }
}

// KFALL (gated, single block): exact fallback if the T0 prefilter window
// fails. Never taken for the bench distribution; correctness backstop only.
// LDS histogram (32 KB) -> threshold bin -> compact into cand via meta[3].
__global__ void __launch_bounds__(1024)
kfall(const float* __restrict__ obj,
      const float* __restrict__ cls,
      float* __restrict__ scores,
      int* __restrict__ meta,
      u64* __restrict__ cand, int M) {
    int C = meta[2];
    if (C >= TOPK_N && C <= CAND_CAP) return;     // fast path succeeded
    __shared__ unsigned hist[NB2];                // 32 KB
    __shared__ unsigned wsum[16], woff[16];
    __shared__ int bbin;
    int t = threadIdx.x;                          // 1024
    int lane = t & 63, w = t >> 6;
    for (int b = t; b < NB2; b += 1024) hist[b] = 0;
    __syncthreads();
    // pass 1: scores + LDS histogram
    for (int a = t; a < M; a += 1024) {
        const float4* row = (const float4*)(cls + (size_t)a * NCLS);
        float m = -1e30f;
        for (int j = 0; j < 20; ++j) {
            float4 v = row[j];
            m = fmaxf(m, fmaxf(fmaxf(v.x, v.y), fmaxf(v.z, v.w)));
        }
        float score = sqrtf(sigmoidf_(obj[a]) * sigmoidf_(m));
        scores[a] = score;
        atomicAdd(&hist[__float_as_uint(score) >> 17], 1u);
    }
    __syncthreads();
    // descending scan: thread t owns bins [base-7 .. base], 8 each
    int base = NB2 - 1 - t * 8;
    unsigned bins[8]; unsigned s = 0;
    #pragma unroll
    for (int k = 0; k < 8; ++k) { bins[k] = hist[base - k]; s += bins[k]; }
    unsigned inc = s;
    for (int d = 1; d < 64; d <<= 1) {
        unsigned pv = __shfl_up(inc, d);
        if (lane >= d) inc += pv;
    }
    if (lane == 63) wsum[w] = inc;
    __syncthreads();
    if (t == 0) {
        unsigned cum = 0;
        for (int i = 0; i < 16; ++i) { woff[i] = cum; cum += wsum[i]; }
    }
    __syncthreads();
    unsigned excl = woff[w] + inc - s;
    if (excl < TOPK_N && excl + s >= TOPK_N) {    // exactly one thread
        unsigned cum = excl; int b = base;
        #pragma unroll
        for (int k = 0; k < 8; ++k) {
            unsigned h = bins[k];
            if (cum + h >= TOPK_N) { bbin = b; break; }
            cum += h; --b;
        }
    }
    __syncthreads();
    int B = bbin;
    // compact (exact: everything at/above threshold bin)
    for (int a = t; a < M; a += 1024) {
        unsigned key = __float_as_uint(scores[a]);
        if ((int)(key >> 17) >= B) {
            int pos = atomicAdd(meta + 3, 1);
            if (pos < CAND_CAP) cand[pos] = make_key2(key, a);
        }
    }
}

// K4: counting-sort rank + fused gather. Histogram over descending score
// bins -> prefix sum -> scatter bin-sorted -> rank -> label argmax + box
// prep for the 1000 winners, all in one block.
__global__ void __launch_bounds__(1024)
k4_rank(const u64* __restrict__ cand,
        const int* __restrict__ meta,
        const float* __restrict__ cls,
        const float4* __restrict__ box,
        float* __restrict__ tkscore,
        int* __restrict__ tklabel,
        float4* __restrict__ boxes_k,
        float4* __restrict__ obx,
        float* __restrict__ areas) {
    __shared__ u64 sorted[CAND_CAP];        // 98304 B
    __shared__ unsigned hist[RBINS];        // exclusive base after prefix
    __shared__ unsigned cnt[RBINS];
    __shared__ int anch_s[TOPK_N];          // rank -> anchor
    __shared__ unsigned wsum[16], woff[16];
    int t = threadIdx.x;                    // 1024
    int lane = t & 63, w = t >> 6;
    int Cf = meta[2];
    bool fast = (Cf >= TOPK_N && Cf <= CAND_CAP);
    int C = fast ? Cf : meta[3];
    if (C > CAND_CAP) C = CAND_CAP;
    for (int b = t; b < RBINS; b += 1024) { hist[b] = 0; cnt[b] = 0; }
    __syncthreads();
    u64 keys[12]; int nk = 0;
    for (int i = t; i < C; i += 1024) {
        u64 k = cand[i];
        keys[nk++] = k;
        atomicAdd(&hist[key_bin(k)], 1u);
    }
    __syncthreads();
    unsigned h0 = hist[t * 3], h1 = hist[t * 3 + 1], h2 = hist[t * 3 + 2];
    unsigned s = h0 + h1 + h2;
    unsigned inc = s;
    for (int d = 1; d < 64; d <<= 1) {
        unsigned pv = __shfl_up(inc, d);
        if (lane >= d) inc += pv;
    }
    if (lane == 63) wsum[w] = inc;
    __syncthreads();
    if (t == 0) {
        unsigned cum = 0;
        for (int i = 0; i < 16; ++i) { woff[i] = cum; cum += wsum[i]; }
    }
    __syncthreads();
    unsigned base = woff[w] + inc - s;
    hist[t * 3] = base;
    hist[t * 3 + 1] = base + h0;
    hist[t * 3 + 2] = base + h0 + h1;
    __syncthreads();
    nk = 0;
    for (int i = t; i < C; i += 1024) {
        u64 k = keys[nk++];
        int b = key_bin(k);
        unsigned pos = hist[b] + atomicAdd(&cnt[b], 1u);
        sorted[pos] = k;
    }
    __syncthreads();
    for (int p = t; p < C; p += 1024) {
        u64 k = sorted[p];
        int b = key_bin(k);
        unsigned b0 = hist[b], b1 = b0 + cnt[b];
        int r = (int)b0;
        for (unsigned q = b0; q < b1; ++q) r += (sorted[q] > k);
        if (r < TOPK_N) {
            tkscore[r] = __uint_as_float((unsigned)(k >> 19));
            anch_s[r] = ANCH_INV - (int)(k & 0x7FFFF);
        }
    }
    __syncthreads();
    // gather phase: 64 groups x 16 lanes; label argmax + box prep per rank
    int grp = t >> 4, l = t & 15;
    for (int r = grp; r < TOPK_N; r += 64) {
        int anchor = anch_s[r];
        const float4* row = (const float4*)(cls + (size_t)anchor * NCLS);
        float bv; int bc;
        rowmax16(row, l, bv, bc);
        if (l == 0) {
            tklabel[r] = bc;
            float4 b = box[anchor];
            boxes_k[r] = b;
            float off = (float)bc * 4096.0f;
            float4 ob = make_float4(b.x + off, b.y + off, b.z + off, b.w + off);
            obx[r] = ob;
            areas[r] = fmaxf(ob.z - ob.x, 0.0f) * fmaxf(ob.w - ob.y, 0.0f);
        }
    }
}

// K5: transposed suppression mask: bit j of row i set iff j<i and IoU>0.5.
__global__ void k5_iou(const float4* __restrict__ obx,
                       const float* __restrict__ areas,
                       u64* __restrict__ mask) {
    int i = blockIdx.x * 4 + (threadIdx.x >> 6);
    int lane = threadIdx.x & 63;
    if (i >= TOPK_N) return;
    float4 bi = obx[i];
    float ai = areas[i];
    for (int w = 0; w < 16; ++w) {
        int c = w * 64 + lane;
        bool bit = false;
        if (c < i) {
            float4 bc = obx[c];
            float xx1 = fmaxf(bi.x, bc.x), yy1 = fmaxf(bi.y, bc.y);
            float xx2 = fminf(bi.z, bc.z), yy2 = fminf(bi.w, bc.w);
            float inter = fmaxf(xx2 - xx1, 0.0f) * fmaxf(yy2 - yy1, 0.0f);
            float iou = inter / (ai + areas[c] - inter + 1e-9f);
            bit = iou > 0.5f;
        }
        u64 bal = __ballot(bit);
        if (lane == 0) mask[(size_t)i * 16 + w] = bal;
    }
}

// K6: atomic-free parallel exact greedy NMS + fused output write.
__global__ void __launch_bounds__(1024)
k6_nms(const float* __restrict__ tkscore,
       const u64* __restrict__ mask,
       const int* __restrict__ tklabel,
       const float4* __restrict__ boxes_k,
       float* __restrict__ out) {
    __shared__ u64 kept_s[16], dec_s[16];
    int t = threadIdx.x, w = t >> 6, lane = t & 63;
    bool active = t < TOPK_N;
    u64 sup[16];
    float sc = 0.0f;
    if (active) {
        #pragma unroll
        for (int q = 0; q < 16; ++q) sup[q] = mask[(size_t)t * 16 + q];
        sc = tkscore[t];
    } else {
        #pragma unroll
        for (int q = 0; q < 16; ++q) sup[q] = 0ULL;
    }
    bool conf = active && (sc > 0.001f);
    bool mydec = !conf;
    bool mykept = false;
    u64 db = __ballot(mydec), kb = __ballot(mykept);
    if (lane == 0) { dec_s[w] = db; kept_s[w] = kb; }
    __syncthreads();
    for (int round = 0; round < TOPK_N; ++round) {
        if (!mydec) {
            u64 pend = 0;
            #pragma unroll
            for (int q = 0; q < 16; ++q) pend |= sup[q] & ~dec_s[q];
            if (pend == 0ULL) {
                u64 kk = 0;
                #pragma unroll
                for (int q = 0; q < 16; ++q) kk |= sup[q] & kept_s[q];
                mydec = true; mykept = (kk == 0ULL);
            }
        }
        __syncthreads();
        db = __ballot(mydec); kb = __ballot(mykept);
        if (lane == 0) { dec_s[w] = db; kept_s[w] = kb; }
        __syncthreads();
        u64 a = ~0ULL;
        #pragma unroll
        for (int q = 0; q < 16; ++q) a &= dec_s[q];
        if (a == ~0ULL) break;
    }
    if (active) {
        float k = mykept ? 1.0f : 0.0f;
        float4 b = boxes_k[t];
        out[t * 5 + 0] = sc * k;
        out[t * 5 + 1] = b.x * k;
        out[t * 5 + 2] = b.y * k;
        out[t * 5 + 3] = b.z * k;
        out[t * 5 + 4] = b.w * k;
        out[5 * TOPK_N + t] = (float)tklabel[t];
        out[6 * TOPK_N + t] = k;
    }
}

extern "C" void kernel_launch(void* const* d_in, const int* in_sizes, int n_in,
                              void* d_out, int out_size, void* d_ws, size_t ws_size,
                              hipStream_t stream) {
    const float* obj = (const float*)d_in[0];
    const float* cls = (const float*)d_in[1];
    const float* box = (const float*)d_in[2];
    float* out = (float*)d_out;
    char* ws = (char*)d_ws;
    int M = in_sizes[0];   // 300000

    float*    scores  = (float*)(ws + WS_SCORES);
    u64*      cand    = (u64*)(ws + WS_CAND);
    float*    tkscore = (float*)(ws + WS_TKSCORE);
    int*      tklabel = (int*)(ws + WS_TKLABEL);
    float4*   boxes_k = (float4*)(ws + WS_BOXES);
    float4*   obx     = (float4*)(ws + WS_OBX);
    float*    areas   = (float*)(ws + WS_AREAS);
    u64*      mask    = (u64*)(ws + WS_MASK);
    int*      meta    = (int*)(ws + WS_META);

    hipMemsetAsync(ws + WS_META, 0, 64, stream);

    k1_scores<<<(M + 63) / 64, 256, 0, stream>>>(obj, cls, cand, meta + 2, M);
    kfall<<<1, 1024, 0, stream>>>(obj, cls, scores, meta, cand, M);
    k4_rank<<<1, 1024, 0, stream>>>(cand, meta, cls, (const float4*)box,
                                    tkscore, tklabel, boxes_k, obx, areas);
    k5_iou<<<(TOPK_N + 3) / 4, 256, 0, stream>>>(obx, areas, mask);
    k6_nms<<<1, 1024, 0, stream>>>(tkscore, mask, tklabel, boxes_k, out);
}

// Round 10
// 192.811 us; speedup vs baseline: 1.0833x; 1.0833x over previous
//
#include <hip/hip_runtime.h>
#include <hip/hip_bf16.h>
#include <math.h>

#define NCLS 80
#define TOPK_N 1000
#define CAND_CAP 12288
#define T0 0.91f                // fast-path score threshold (exactness gated)
#define NB2 8192                // fallback LDS histogram bins = key >> 17
#define RBINS 3072              // rank bins (k4 counting sort)
#define RBIN_LO 0x3F680000u     // float bits of ~0.90625
#define ANCH_INV 524287         // 2^19-1, anchor < 300000
#define NEGF -3.4e38f

// ---- workspace layout (bytes), M = 300000 ----
#define WS_SCORES   0           // 300000 f32 (fallback only)
#define WS_CAND     1200000     // 12288 u64 composite keys
#define WS_TKSCORE  1298304     // 1000 f32
#define WS_TKANCH   1302304     // 1000 i32
#define WS_TKLABEL  1306304     // 1000 i32
#define WS_BOXES    1310304     // 1000 float4
#define WS_OBX      1326304     // 1000 float4 (class-offset boxes)
#define WS_AREAS    1342304     // 1000 f32
#define WS_MASK     1346304     // 1000 * 16 u64 transposed sup mask
#define WS_META     1474304     // [2]=fast counter, [3]=fb counter
// end = 1,474,368 B

typedef unsigned long long u64;
typedef float nt_f4 __attribute__((ext_vector_type(4)));  // nontemporal-load-able

__device__ __forceinline__ float sigmoidf_(float x) {
    return 1.0f / (1.0f + expf(-x));
}

// composite key: [50:19]=score bits, [18:0]=(2^19-1-anchor).
// u64 descending == (score desc, anchor asc); (score,anchor) unique.
__device__ __forceinline__ u64 make_key2(unsigned s32, int anchor) {
    return ((u64)s32 << 19) | (unsigned)(ANCH_INV - anchor);
}

// BIN 0 = HIGHEST scores (descending bins): ascending-bin exclusive prefix
// sum = "# elements in higher-score bins" = correct rank base.
__device__ __forceinline__ int key_bin(u64 k) {
    unsigned s32 = (unsigned)(k >> 19);
    int d = (int)(s32 - RBIN_LO);
    if (d < 0) d = 0;
    int b = d >> 9;
    if (b > RBINS - 1) b = RBINS - 1;
    return (RBINS - 1) - b;
}

// row max+argmax over 80 classes with 16 lanes (l = lane & 15), first-max tie
__device__ __forceinline__ void rowmax16(const float4* row, int l,
                                         float& bv, int& bc) {
    float4 v4 = row[l];
    bv = v4.x; bc = l * 4;
    if (v4.y > bv) { bv = v4.y; bc = l * 4 + 1; }
    if (v4.z > bv) { bv = v4.z; bc = l * 4 + 2; }
    if (v4.w > bv) { bv = v4.w; bc = l * 4 + 3; }
    if (l < 4) {
        float4 w4 = row[16 + l];
        int cb = 64 + l * 4;
        if (w4.x > bv) { bv = w4.x; bc = cb; }
        if (w4.y > bv) { bv = w4.y; bc = cb + 1; }
        if (w4.z > bv) { bv = w4.z; bc = cb + 2; }
        if (w4.w > bv) { bv = w4.w; bc = cb + 3; }
    }
    #pragma unroll
    for (int m = 8; m >= 1; m >>= 1) {
        float ov = __shfl_xor(bv, m);
        int oc = __shfl_xor(bc, m);
        if (ov > bv || (ov == bv && oc < bc)) { bv = ov; bc = oc; }
    }
}

__device__ __forceinline__ float max4v(nt_f4 v) {
    return fmaxf(fmaxf(v.x, v.y), fmaxf(v.z, v.w));
}
__device__ __forceinline__ float max4(float4 v) {
    return fmaxf(fmaxf(v.x, v.y), fmaxf(v.z, v.w));
}

// K1 (fast path): max-only score scan. A 16-lane group covers its 4 rows'
// 80 float4s with 5 DENSE loads/lane (p[l+16k], no divergent tail); row
// maxes reassembled via masked selects. Nontemporal cls loads (pure stream).
__global__ void __launch_bounds__(256)
k1_scores(const float* __restrict__ obj,
          const float* __restrict__ cls,
          u64* __restrict__ cand,
          int* __restrict__ counter, int M) {
    __shared__ int lcount, lbase;
    __shared__ u64 lkeys[64];
    int t = threadIdx.x;
    if (t == 0) lcount = 0;
    __syncthreads();
    int l = t & 15;
    int grp = t >> 4;                         // 16 groups/block
    int base = blockIdx.x * 64 + grp * 4;     // 4 rows/group
    if (base < M) {                           // uniform per group; M%4==0
        const nt_f4* p = (const nt_f4*)(cls + (size_t)base * NCLS);
        nt_f4 q0 = __builtin_nontemporal_load(&p[l]);
        nt_f4 q1 = __builtin_nontemporal_load(&p[l + 16]);
        nt_f4 q2 = __builtin_nontemporal_load(&p[l + 32]);
        nt_f4 q3 = __builtin_nontemporal_load(&p[l + 48]);
        nt_f4 q4 = __builtin_nontemporal_load(&p[l + 64]);
        float m0 = max4v(q0), m1 = max4v(q1), m2 = max4v(q2),
              m3 = max4v(q3), m4 = max4v(q4);
        // float4 j=l+16k belongs to row (l+16k)/20:
        //  q0: row0 | q1: l<4 row0 else row1 | q2: l<8 row1 else row2
        //  q3: l<12 row2 else row3 | q4: row3
        float z0 = fmaxf(m0, (l < 4)  ? m1 : NEGF);
        float z1 = fmaxf((l >= 4)  ? m1 : NEGF, (l < 8)  ? m2 : NEGF);
        float z2 = fmaxf((l >= 8)  ? m2 : NEGF, (l < 12) ? m3 : NEGF);
        float z3 = fmaxf((l >= 12) ? m3 : NEGF, m4);
        #pragma unroll
        for (int s = 8; s >= 1; s >>= 1) {
            z0 = fmaxf(z0, __shfl_xor(z0, s));
            z1 = fmaxf(z1, __shfl_xor(z1, s));
            z2 = fmaxf(z2, __shfl_xor(z2, s));
            z3 = fmaxf(z3, __shfl_xor(z3, s));
        }
        if (l < 4) {
            float mm = (l < 2) ? ((l == 0) ? z0 : z1) : ((l == 2) ? z2 : z3);
            int anchor = base + l;
            float score = sqrtf(sigmoidf_(obj[anchor]) * sigmoidf_(mm));
            if (score > T0) {
                int pos = atomicAdd(&lcount, 1);
                lkeys[pos] = make_key2(__float_as_uint(score), anchor);
            }
        }
    }
    __syncthreads();
    if (t == 0 && lcount > 0) lbase = atomicAdd(counter, lcount);
    __syncthreads();
    int n = lcount;
    if (t < n) {
        int pos = lbase + t;
        if (pos < CAND_CAP) cand[pos] = lkeys[t];
    }
}

// KFALL (gated, single block): exact fallback if the T0 prefilter window
// fails. Never taken for the bench distribution; correctness backstop only.
__global__ void __launch_bounds__(1024)
kfall(const float* __restrict__ obj,
      const float* __restrict__ cls,
      float* __restrict__ scores,
      int* __restrict__ meta,
      u64* __restrict__ cand, int M) {
    int C = meta[2];
    if (C >= TOPK_N && C <= CAND_CAP) return;     // fast path succeeded
    __shared__ unsigned hist[NB2];                // 32 KB
    __shared__ unsigned wsum[16], woff[16];
    __shared__ int bbin;
    int t = threadIdx.x;                          // 1024
    int lane = t & 63, w = t >> 6;
    for (int b = t; b < NB2; b += 1024) hist[b] = 0;
    __syncthreads();
    for (int a = t; a < M; a += 1024) {
        const float4* row = (const float4*)(cls + (size_t)a * NCLS);
        float m = NEGF;
        for (int j = 0; j < 20; ++j) m = fmaxf(m, max4(row[j]));
        float score = sqrtf(sigmoidf_(obj[a]) * sigmoidf_(m));
        scores[a] = score;
        atomicAdd(&hist[__float_as_uint(score) >> 17], 1u);
    }
    __syncthreads();
    int base = NB2 - 1 - t * 8;
    unsigned bins[8]; unsigned s = 0;
    #pragma unroll
    for (int k = 0; k < 8; ++k) { bins[k] = hist[base - k]; s += bins[k]; }
    unsigned inc = s;
    for (int d = 1; d < 64; d <<= 1) {
        unsigned pv = __shfl_up(inc, d);
        if (lane >= d) inc += pv;
    }
    if (lane == 63) wsum[w] = inc;
    __syncthreads();
    if (t == 0) {
        unsigned cum = 0;
        for (int i = 0; i < 16; ++i) { woff[i] = cum; cum += wsum[i]; }
    }
    __syncthreads();
    unsigned excl = woff[w] + inc - s;
    if (excl < TOPK_N && excl + s >= TOPK_N) {    // exactly one thread
        unsigned cum = excl; int b = base;
        #pragma unroll
        for (int k = 0; k < 8; ++k) {
            unsigned h = bins[k];
            if (cum + h >= TOPK_N) { bbin = b; break; }
            cum += h; --b;
        }
    }
    __syncthreads();
    int B = bbin;
    for (int a = t; a < M; a += 1024) {
        unsigned key = __float_as_uint(scores[a]);
        if ((int)(key >> 17) >= B) {
            int pos = atomicAdd(meta + 3, 1);
            if (pos < CAND_CAP) cand[pos] = make_key2(key, a);
        }
    }
}

// K4: counting-sort rank -> (tkscore, tkanchor). O(C), one block.
__global__ void __launch_bounds__(1024)
k4_rank(const u64* __restrict__ cand,
        const int* __restrict__ meta,
        float* __restrict__ tkscore,
        int* __restrict__ tkanchor) {
    __shared__ u64 sorted[CAND_CAP];        // 98304 B
    __shared__ unsigned hist[RBINS];        // exclusive base after prefix
    __shared__ unsigned cnt[RBINS];
    __shared__ unsigned wsum[16], woff[16];
    int t = threadIdx.x;                    // 1024
    int lane = t & 63, w = t >> 6;
    int Cf = meta[2];
    bool fast = (Cf >= TOPK_N && Cf <= CAND_CAP);
    int C = fast ? Cf : meta[3];
    if (C > CAND_CAP) C = CAND_CAP;
    for (int b = t; b < RBINS; b += 1024) { hist[b] = 0; cnt[b] = 0; }
    __syncthreads();
    u64 keys[12]; int nk = 0;
    for (int i = t; i < C; i += 1024) {
        u64 k = cand[i];
        keys[nk++] = k;
        atomicAdd(&hist[key_bin(k)], 1u);
    }
    __syncthreads();
    unsigned h0 = hist[t * 3], h1 = hist[t * 3 + 1], h2 = hist[t * 3 + 2];
    unsigned s = h0 + h1 + h2;
    unsigned inc = s;
    for (int d = 1; d < 64; d <<= 1) {
        unsigned pv = __shfl_up(inc, d);
        if (lane >= d) inc += pv;
    }
    if (lane == 63) wsum[w] = inc;
    __syncthreads();
    if (t == 0) {
        unsigned cum = 0;
        for (int i = 0; i < 16; ++i) { woff[i] = cum; cum += wsum[i]; }
    }
    __syncthreads();
    unsigned base = woff[w] + inc - s;
    hist[t * 3] = base;
    hist[t * 3 + 1] = base + h0;
    hist[t * 3 + 2] = base + h0 + h1;
    __syncthreads();
    nk = 0;
    for (int i = t; i < C; i += 1024) {
        u64 k = keys[nk++];
        int b = key_bin(k);
        unsigned pos = hist[b] + atomicAdd(&cnt[b], 1u);
        sorted[pos] = k;
    }
    __syncthreads();
    for (int p = t; p < C; p += 1024) {
        u64 k = sorted[p];
        int b = key_bin(k);
        unsigned b0 = hist[b], b1 = b0 + cnt[b];
        int r = (int)b0;
        for (unsigned q = b0; q < b1; ++q) r += (sorted[q] > k);
        if (r < TOPK_N) {
            tkscore[r] = __uint_as_float((unsigned)(k >> 19));
            tkanchor[r] = ANCH_INV - (int)(k & 0x7FFFF);
        }
    }
}

// K4b (multi-block): per-rank label argmax + box/obx/area gather.
// 16 lanes per rank, 16 ranks per block — parallel across CUs.
__global__ void __launch_bounds__(256)
k4b_gather(const float* __restrict__ cls,
           const float4* __restrict__ box,
           const int* __restrict__ tkanchor,
           int* __restrict__ tklabel,
           float4* __restrict__ boxes_k,
           float4* __restrict__ obx,
           float* __restrict__ areas) {
    int grp = threadIdx.x >> 4, l = threadIdx.x & 15;
    int r = blockIdx.x * 16 + grp;
    if (r >= TOPK_N) return;
    int anchor = tkanchor[r];
    const float4* row = (const float4*)(cls + (size_t)anchor * NCLS);
    float bv; int bc;
    rowmax16(row, l, bv, bc);
    if (l == 0) {
        tklabel[r] = bc;
        float4 b = box[anchor];
        boxes_k[r] = b;
        float off = (float)bc * 4096.0f;
        float4 ob = make_float4(b.x + off, b.y + off, b.z + off, b.w + off);
        obx[r] = ob;
        areas[r] = fmaxf(ob.z - ob.x, 0.0f) * fmaxf(ob.w - ob.y, 0.0f);
    }
}

// K5: transposed suppression mask: bit j of row i set iff j<i and IoU>0.5.
__global__ void k5_iou(const float4* __restrict__ obx,
                       const float* __restrict__ areas,
                       u64* __restrict__ mask) {
    int i = blockIdx.x * 4 + (threadIdx.x >> 6);
    int lane = threadIdx.x & 63;
    if (i >= TOPK_N) return;
    float4 bi = obx[i];
    float ai = areas[i];
    for (int w = 0; w < 16; ++w) {
        int c = w * 64 + lane;
        bool bit = false;
        if (c < i) {
            float4 bc = obx[c];
            float xx1 = fmaxf(bi.x, bc.x), yy1 = fmaxf(bi.y, bc.y);
            float xx2 = fminf(bi.z, bc.z), yy2 = fminf(bi.w, bc.w);
            float inter = fmaxf(xx2 - xx1, 0.0f) * fmaxf(yy2 - yy1, 0.0f);
            float iou = inter / (ai + areas[c] - inter + 1e-9f);
            bit = iou > 0.5f;
        }
        u64 bal = __ballot(bit);
        if (lane == 0) mask[(size_t)i * 16 + w] = bal;
    }
}

// K6: atomic-free parallel exact greedy NMS + fused output write.
__global__ void __launch_bounds__(1024)
k6_nms(const float* __restrict__ tkscore,
       const u64* __restrict__ mask,
       const int* __restrict__ tklabel,
       const float4* __restrict__ boxes_k,
       float* __restrict__ out) {
    __shared__ u64 kept_s[16], dec_s[16];
    int t = threadIdx.x, w = t >> 6, lane = t & 63;
    bool active = t < TOPK_N;
    u64 sup[16];
    float sc = 0.0f;
    if (active) {
        #pragma unroll
        for (int q = 0; q < 16; ++q) sup[q] = mask[(size_t)t * 16 + q];
        sc = tkscore[t];
    } else {
        #pragma unroll
        for (int q = 0; q < 16; ++q) sup[q] = 0ULL;
    }
    bool conf = active && (sc > 0.001f);
    bool mydec = !conf;
    bool mykept = false;
    u64 db = __ballot(mydec), kb = __ballot(mykept);
    if (lane == 0) { dec_s[w] = db; kept_s[w] = kb; }
    __syncthreads();
    for (int round = 0; round < TOPK_N; ++round) {
        if (!mydec) {
            u64 pend = 0;
            #pragma unroll
            for (int q = 0; q < 16; ++q) pend |= sup[q] & ~dec_s[q];
            if (pend == 0ULL) {
                u64 kk = 0;
                #pragma unroll
                for (int q = 0; q < 16; ++q) kk |= sup[q] & kept_s[q];
                mydec = true; mykept = (kk == 0ULL);
            }
        }
        __syncthreads();
        db = __ballot(mydec); kb = __ballot(mykept);
        if (lane == 0) { dec_s[w] = db; kept_s[w] = kb; }
        __syncthreads();
        u64 a = ~0ULL;
        #pragma unroll
        for (int q = 0; q < 16; ++q) a &= dec_s[q];
        if (a == ~0ULL) break;
    }
    if (active) {
        float k = mykept ? 1.0f : 0.0f;
        float4 b = boxes_k[t];
        out[t * 5 + 0] = sc * k;
        out[t * 5 + 1] = b.x * k;
        out[t * 5 + 2] = b.y * k;
        out[t * 5 + 3] = b.z * k;
        out[t * 5 + 4] = b.w * k;
        out[5 * TOPK_N + t] = (float)tklabel[t];
        out[6 * TOPK_N + t] = k;
    }
}

extern "C" void kernel_launch(void* const* d_in, const int* in_sizes, int n_in,
                              void* d_out, int out_size, void* d_ws, size_t ws_size,
                              hipStream_t stream) {
    const float* obj = (const float*)d_in[0];
    const float* cls = (const float*)d_in[1];
    const float* box = (const float*)d_in[2];
    float* out = (float*)d_out;
    char* ws = (char*)d_ws;
    int M = in_sizes[0];   // 300000

    float*    scores  = (float*)(ws + WS_SCORES);
    u64*      cand    = (u64*)(ws + WS_CAND);
    float*    tkscore = (float*)(ws + WS_TKSCORE);
    int*      tkanch  = (int*)(ws + WS_TKANCH);
    int*      tklabel = (int*)(ws + WS_TKLABEL);
    float4*   boxes_k = (float4*)(ws + WS_BOXES);
    float4*   obx     = (float4*)(ws + WS_OBX);
    float*    areas   = (float*)(ws + WS_AREAS);
    u64*      mask    = (u64*)(ws + WS_MASK);
    int*      meta    = (int*)(ws + WS_META);

    (void)hipMemsetAsync(ws + WS_META, 0, 64, stream);

    k1_scores<<<(M + 63) / 64, 256, 0, stream>>>(obj, cls, cand, meta + 2, M);
    kfall<<<1, 1024, 0, stream>>>(obj, cls, scores, meta, cand, M);
    k4_rank<<<1, 1024, 0, stream>>>(cand, meta, tkscore, tkanch);
    k4b_gather<<<(TOPK_N + 15) / 16, 256, 0, stream>>>(cls, (const float4*)box,
                                                       tkanch, tklabel, boxes_k, obx, areas);
    k5_iou<<<(TOPK_N + 3) / 4, 256, 0, stream>>>(obx, areas, mask);
    k6_nms<<<1, 1024, 0, stream>>>(tkscore, mask, tklabel, boxes_k, out);
}